// Round 1
// baseline (1549.909 us; speedup 1.0000x reference)
//
#include <hip/hip_runtime.h>
#include <hip/hip_bf16.h>
#include <stdint.h>

#define NTOK 8192          // B*L = 8*1024
#define DM   1024

typedef __bf16 bf16x8 __attribute__((ext_vector_type(8)));
typedef float  f32x4  __attribute__((ext_vector_type(4)));

__device__ __forceinline__ unsigned short f2bf(float f) {
  union { float f; unsigned u; } v; v.f = f;
  unsigned r = v.u + 0x7FFFu + ((v.u >> 16) & 1u);   // round-to-nearest-even
  return (unsigned short)(r >> 16);
}

// ---------------- convert x: fp32 [tok][3][1024] -> bf16 [s][tok][1024] ----------------
__global__ void convert_x(const float* __restrict__ x, unsigned short* __restrict__ Xbf) {
  int idx = (blockIdx.x * 256 + threadIdx.x) * 4;
  int s   = idx >> 23;               // / (8192*1024)
  int rem = idx & ((1 << 23) - 1);
  int tok = rem >> 10;
  int d   = rem & 1023;
  const float4 v = *(const float4*)&x[((size_t)tok * 3 + s) * 1024 + d];
  ushort4 o;
  o.x = f2bf(v.x); o.y = f2bf(v.y); o.z = f2bf(v.z); o.w = f2bf(v.w);
  *(ushort4*)&Xbf[idx] = o;
}

// ---------------- W (K x N fp32) -> Wt (N x K bf16), 1024x1024 ----------------
__global__ void transpose_w(const float* __restrict__ W, unsigned short* __restrict__ Wt) {
  __shared__ float t[32][33];
  int tx = threadIdx.x, ty = threadIdx.y;            // block (32,8)
  int bx = blockIdx.x * 32, by = blockIdx.y * 32;
#pragma unroll
  for (int i = 0; i < 32; i += 8)
    t[ty + i][tx] = W[(size_t)(by + ty + i) * 1024 + bx + tx];
  __syncthreads();
#pragma unroll
  for (int i = 0; i < 32; i += 8)
    Wt[(size_t)(bx + ty + i) * 1024 + by + tx] = f2bf(t[tx][ty + i]);  // Wt[n][k]=W[k][n]
}

// ---------------- shared 128x128 GEMM core, A: Mx1024 bf16, Bt: Nx1024 bf16 ----------------
__device__ __forceinline__ void gemm128_core(
    const unsigned short* __restrict__ A, const unsigned short* __restrict__ Bt,
    unsigned short* lA, unsigned short* lB, f32x4 acc[4][4])
{
  int tid  = threadIdx.x;
  int wave = tid >> 6, lane = tid & 63, quad = lane >> 4, l16 = lane & 15;
  int m0 = blockIdx.y * 128, n0 = blockIdx.x * 128;
  int r0 = tid >> 2, kc = (tid & 3) * 8;             // 512 16B-chunks per tile
  const unsigned short* Ag = A  + (size_t)(m0 + r0) * 1024 + kc;
  const unsigned short* Bg = Bt + (size_t)(n0 + r0) * 1024 + kc;
  int wm = (wave >> 1) * 64, wn = (wave & 1) * 64;

  for (int k0 = 0; k0 < 1024; k0 += 32) {
    *(uint4*)&lA[r0 * 32 + kc]        = *(const uint4*)&Ag[k0];
    *(uint4*)&lA[(r0 + 64) * 32 + kc] = *(const uint4*)&Ag[k0 + 64 * 1024];
    *(uint4*)&lB[r0 * 32 + kc]        = *(const uint4*)&Bg[k0];
    *(uint4*)&lB[(r0 + 64) * 32 + kc] = *(const uint4*)&Bg[k0 + 64 * 1024];
    __syncthreads();
    bf16x8 af[4], bfr[4];
#pragma unroll
    for (int i = 0; i < 4; i++) {
      af[i]  = *(const bf16x8*)&lA[(wm + i * 16 + l16) * 32 + quad * 8];
      bfr[i] = *(const bf16x8*)&lB[(wn + i * 16 + l16) * 32 + quad * 8];
    }
#pragma unroll
    for (int mi = 0; mi < 4; mi++)
#pragma unroll
      for (int ni = 0; ni < 4; ni++)
        acc[mi][ni] = __builtin_amdgcn_mfma_f32_16x16x32_bf16(af[mi], bfr[ni], acc[mi][ni], 0, 0, 0);
    __syncthreads();
  }
}

// ---------------- 9 projection GEMMs: P[s*3+w] = Xbf[s] @ W[w] + bias[w], bf16 out ----------------
__global__ __launch_bounds__(256, 2) void gemm_proj(
    const unsigned short* __restrict__ Xbf, const unsigned short* __restrict__ Wt,
    unsigned short* __restrict__ P,
    const float* __restrict__ bq, const float* __restrict__ bk, const float* __restrict__ bv)
{
  __shared__ unsigned short lA[128 * 32];
  __shared__ unsigned short lB[128 * 32];
  int z = blockIdx.z, s = z / 3, w = z - s * 3;
  const float* bias = (w == 0) ? bq : (w == 1) ? bk : bv;
  f32x4 acc[4][4];
#pragma unroll
  for (int i = 0; i < 4; i++)
#pragma unroll
    for (int j = 0; j < 4; j++) acc[i][j] = (f32x4){0.f, 0.f, 0.f, 0.f};
  gemm128_core(Xbf + (size_t)s * NTOK * 1024, Wt + (size_t)w * 1024 * 1024, lA, lB, acc);

  int tid = threadIdx.x, wave = tid >> 6, lane = tid & 63, quad = lane >> 4, l16 = lane & 15;
  int m0 = blockIdx.y * 128 + (wave >> 1) * 64;
  int n0 = blockIdx.x * 128 + (wave & 1) * 64;
  unsigned short* C = P + (size_t)z * NTOK * 1024;
#pragma unroll
  for (int mi = 0; mi < 4; mi++)
#pragma unroll
    for (int ni = 0; ni < 4; ni++) {
      int col = n0 + ni * 16 + l16;
      float bcol = bias[col];
#pragma unroll
      for (int r = 0; r < 4; r++) {
        int row = m0 + mi * 16 + quad * 4 + r;
        C[(size_t)row * 1024 + col] = f2bf(acc[mi][ni][r] + bcol);
      }
    }
}

// ---------------- V transpose: P[s*3+2] (tok x (h*64+d)) -> Vt[(s,b,h)] (64d x 1024l) ----------------
__global__ void transpose_v(const unsigned short* __restrict__ P, unsigned short* __restrict__ Vt) {
  __shared__ unsigned short t[64][65];
  int z = blockIdx.z;                 // s*128 + b*16 + h
  int s = z >> 7, bh = z & 127, h = bh & 15, b = bh >> 4;
  int l0 = blockIdx.x * 64;
  const unsigned short* src = P + (size_t)(s * 3 + 2) * NTOK * 1024
                                + (size_t)b * 1024 * 1024 + h * 64;
#pragma unroll
  for (int i = 0; i < 64; i += 8)
    t[threadIdx.y + i][threadIdx.x] = src[(size_t)(l0 + threadIdx.y + i) * 1024 + threadIdx.x];
  __syncthreads();
  unsigned short* dst = Vt + (size_t)z * 65536;   // [d][l], row stride 1024
#pragma unroll
  for (int i = 0; i < 64; i += 8)
    dst[(size_t)(threadIdx.y + i) * 1024 + l0 + threadIdx.x] = t[threadIdx.x][threadIdx.y + i];
}

// ---------------- fused dual attention (no-max softmax: logits std ~0.7, fp32-safe) ----------------
__global__ __launch_bounds__(256, 2) void attn(
    const unsigned short* __restrict__ P, const unsigned short* __restrict__ Vt,
    unsigned short* __restrict__ Oa)
{
  __shared__ alignas(16) unsigned short pls[4][512];   // per-wave 16q x 32k bf16 P tile
  int o  = blockIdx.z;
  int As = (o == 0) ? 1 : 0;          // first (q,k) source stream
  int Bs = (o == 2) ? 1 : 2;          // second (q,k) source stream
  int b = blockIdx.y >> 4, h = blockIdx.y & 15;
  int tid = threadIdx.x, wave = tid >> 6, lane = tid & 63, quad = lane >> 4, l16 = lane & 15;
  int q0 = blockIdx.x * 64 + wave * 16;
  size_t bh_off = (size_t)b * 1024 * 1024 + h * 64;
  const unsigned short* Q1 = P + (size_t)(As * 3 + 0) * NTOK * 1024 + bh_off;
  const unsigned short* K1 = P + (size_t)(As * 3 + 1) * NTOK * 1024 + bh_off;
  const unsigned short* Q2 = P + (size_t)(Bs * 3 + 0) * NTOK * 1024 + bh_off;
  const unsigned short* K2 = P + (size_t)(Bs * 3 + 1) * NTOK * 1024 + bh_off;
  const unsigned short* V  = Vt + (size_t)((o * 8 + b) * 16 + h) * 65536;
  unsigned short* myp = pls[wave];

  bf16x8 q1f[2], q2f[2];
#pragma unroll
  for (int c = 0; c < 2; c++) {
    q1f[c] = *(const bf16x8*)&Q1[(size_t)(q0 + l16) * 1024 + c * 32 + quad * 8];
    q2f[c] = *(const bf16x8*)&Q2[(size_t)(q0 + l16) * 1024 + c * 32 + quad * 8];
  }
  bf16x8 ones;
#pragma unroll
  for (int j = 0; j < 8; j++) ones[j] = (__bf16)1.0f;

  f32x4 oacc[4];
#pragma unroll
  for (int i = 0; i < 4; i++) oacc[i] = (f32x4){0.f, 0.f, 0.f, 0.f};
  f32x4 lsum = (f32x4){0.f, 0.f, 0.f, 0.f};

  for (int k0 = 0; k0 < 1024; k0 += 32) {
    f32x4 sacc[2];
    sacc[0] = (f32x4){0.f, 0.f, 0.f, 0.f};
    sacc[1] = (f32x4){0.f, 0.f, 0.f, 0.f};
#pragma unroll
    for (int g = 0; g < 2; g++) {
#pragma unroll
      for (int c = 0; c < 2; c++) {
        bf16x8 kf1 = *(const bf16x8*)&K1[(size_t)(k0 + g * 16 + l16) * 1024 + c * 32 + quad * 8];
        sacc[g] = __builtin_amdgcn_mfma_f32_16x16x32_bf16(q1f[c], kf1, sacc[g], 0, 0, 0);
        bf16x8 kf2 = *(const bf16x8*)&K2[(size_t)(k0 + g * 16 + l16) * 1024 + c * 32 + quad * 8];
        sacc[g] = __builtin_amdgcn_mfma_f32_16x16x32_bf16(q2f[c], kf2, sacc[g], 0, 0, 0);
      }
    }
    // exp, write P-tile (C-layout) to per-wave LDS
#pragma unroll
    for (int g = 0; g < 2; g++)
#pragma unroll
      for (int r = 0; r < 4; r++) {
        float p = __expf(sacc[g][r] * 0.0625f);   // scale = 1/sqrt(64) * 0.5
        myp[(quad * 4 + r) * 32 + g * 16 + l16] = f2bf(p);
      }
    // read back in A-operand layout (same wave; DS ops are wave-ordered)
    bf16x8 pa = *(const bf16x8*)&myp[l16 * 32 + quad * 8];
    lsum = __builtin_amdgcn_mfma_f32_16x16x32_bf16(pa, ones, lsum, 0, 0, 0);  // row sums
#pragma unroll
    for (int db = 0; db < 4; db++) {
      bf16x8 vf = *(const bf16x8*)&V[(size_t)(db * 16 + l16) * 1024 + k0 + quad * 8];
      oacc[db] = __builtin_amdgcn_mfma_f32_16x16x32_bf16(pa, vf, oacc[db], 0, 0, 0);
    }
  }
  unsigned short* Od = Oa + (size_t)o * NTOK * 1024 + bh_off;
#pragma unroll
  for (int db = 0; db < 4; db++)
#pragma unroll
    for (int r = 0; r < 4; r++) {
      float val = oacc[db][r] / lsum[r];
      Od[(size_t)(q0 + quad * 4 + r) * 1024 + db * 16 + l16] = f2bf(val);
    }
}

// ---------------- output GEMM: d_out[tok][s][:] = Oa[s] @ Wo + bo (fp32) ----------------
__global__ __launch_bounds__(256, 2) void gemm_out(
    const unsigned short* __restrict__ Oattn, const unsigned short* __restrict__ WtO,
    float* __restrict__ out, const float* __restrict__ bo)
{
  __shared__ unsigned short lA[128 * 32];
  __shared__ unsigned short lB[128 * 32];
  int s = blockIdx.z;
  f32x4 acc[4][4];
#pragma unroll
  for (int i = 0; i < 4; i++)
#pragma unroll
    for (int j = 0; j < 4; j++) acc[i][j] = (f32x4){0.f, 0.f, 0.f, 0.f};
  gemm128_core(Oattn + (size_t)s * NTOK * 1024, WtO, lA, lB, acc);

  int tid = threadIdx.x, wave = tid >> 6, lane = tid & 63, quad = lane >> 4, l16 = lane & 15;
  int m0 = blockIdx.y * 128 + (wave >> 1) * 64;
  int n0 = blockIdx.x * 128 + (wave & 1) * 64;
#pragma unroll
  for (int mi = 0; mi < 4; mi++)
#pragma unroll
    for (int ni = 0; ni < 4; ni++) {
      int col = n0 + ni * 16 + l16;
      float bcol = bo[col];
#pragma unroll
      for (int r = 0; r < 4; r++) {
        int row = m0 + mi * 16 + quad * 4 + r;
        out[(size_t)row * 3072 + s * 1024 + col] = acc[mi][ni][r] + bcol;
      }
    }
}

extern "C" void kernel_launch(void* const* d_in, const int* in_sizes, int n_in,
                              void* d_out, int out_size, void* d_ws, size_t ws_size,
                              hipStream_t stream) {
  (void)in_sizes; (void)n_in; (void)out_size; (void)ws_size;
  const float* x  = (const float*)d_in[0];
  const float* Wq = (const float*)d_in[1];
  const float* bq = (const float*)d_in[2];
  const float* Wk = (const float*)d_in[3];
  const float* bk = (const float*)d_in[4];
  const float* Wv = (const float*)d_in[5];
  const float* bv = (const float*)d_in[6];
  const float* Wo = (const float*)d_in[7];
  const float* bo = (const float*)d_in[8];
  float* out = (float*)d_out;

  char* ws = (char*)d_ws;
  // layout (bytes): Xbf 48MB (aliased by Vt after proj) | Wt 8MB | P 144MB | Oa 48MB
  unsigned short* Xbf = (unsigned short*)(ws + 0);
  unsigned short* Vt  = (unsigned short*)(ws + 0);          // alias: Xbf dead after gemm_proj
  unsigned short* Wt  = (unsigned short*)(ws + 50331648);
  unsigned short* P   = (unsigned short*)(ws + 58720256);
  unsigned short* Oa  = (unsigned short*)(ws + 209715200);

  convert_x<<<24576, 256, 0, stream>>>(x, Xbf);
  dim3 tb(32, 8), tg(32, 32);
  transpose_w<<<tg, tb, 0, stream>>>(Wq, Wt + 0 * 1048576);
  transpose_w<<<tg, tb, 0, stream>>>(Wk, Wt + 1 * 1048576);
  transpose_w<<<tg, tb, 0, stream>>>(Wv, Wt + 2 * 1048576);
  transpose_w<<<tg, tb, 0, stream>>>(Wo, Wt + 3 * 1048576);

  gemm_proj<<<dim3(8, 64, 9), 256, 0, stream>>>(Xbf, Wt, P, bq, bk, bv);
  transpose_v<<<dim3(16, 1, 384), dim3(64, 8), 0, stream>>>(P, Vt);
  attn<<<dim3(16, 128, 3), 256, 0, stream>>>(P, Vt, Oa);
  gemm_out<<<dim3(8, 64, 3), 256, 0, stream>>>(Oa, Wt + 3 * 1048576, out, bo);
}

// Round 2
// 725.063 us; speedup vs baseline: 2.1376x; 2.1376x over previous
//
#include <hip/hip_runtime.h>
#include <hip/hip_bf16.h>
#include <stdint.h>

#define NTOK 8192          // B*L = 8*1024
#define DM   1024

typedef __bf16 bf16x8 __attribute__((ext_vector_type(8)));
typedef float  f32x4  __attribute__((ext_vector_type(4)));

__device__ __forceinline__ unsigned short f2bf(float f) {
  union { float f; unsigned u; } v; v.f = f;
  unsigned r = v.u + 0x7FFFu + ((v.u >> 16) & 1u);   // round-to-nearest-even
  return (unsigned short)(r >> 16);
}

// async global->LDS, 16B per lane; LDS dest = wave-uniform base + lane*16
__device__ __forceinline__ void gld16(const void* g, const void* l) {
  __builtin_amdgcn_global_load_lds(
      (const __attribute__((address_space(1))) uint32_t*)g,
      (__attribute__((address_space(3))) uint32_t*)l, 16, 0, 0);
}

// ---------------- convert x: fp32 [tok][3][1024] -> bf16 [s][tok][1024] ----------------
__global__ void convert_x(const float* __restrict__ x, unsigned short* __restrict__ Xbf) {
  int idx = (blockIdx.x * 256 + threadIdx.x) * 4;
  int s   = idx >> 23;
  int rem = idx & ((1 << 23) - 1);
  int tok = rem >> 10;
  int d   = rem & 1023;
  const float4 v = *(const float4*)&x[((size_t)tok * 3 + s) * 1024 + d];
  ushort4 o;
  o.x = f2bf(v.x); o.y = f2bf(v.y); o.z = f2bf(v.z); o.w = f2bf(v.w);
  *(ushort4*)&Xbf[idx] = o;
}

// ---------------- W (K x N fp32) -> Wt (N x K bf16), 1024x1024 ----------------
__global__ void transpose_w(const float* __restrict__ W, unsigned short* __restrict__ Wt) {
  __shared__ float t[32][33];
  int tx = threadIdx.x, ty = threadIdx.y;            // block (32,8)
  int bx = blockIdx.x * 32, by = blockIdx.y * 32;
#pragma unroll
  for (int i = 0; i < 32; i += 8)
    t[ty + i][tx] = W[(size_t)(by + ty + i) * 1024 + bx + tx];
  __syncthreads();
#pragma unroll
  for (int i = 0; i < 32; i += 8)
    Wt[(size_t)(bx + ty + i) * 1024 + by + tx] = f2bf(t[tx][ty + i]);  // Wt[n][k]=W[k][n]
}

// ---------------- shared 128x128 GEMM core, A: Mx1024 bf16, Bt: Nx1024 bf16 ----------------
__device__ __forceinline__ void gemm128_core(
    const unsigned short* __restrict__ A, const unsigned short* __restrict__ Bt,
    unsigned short* lA, unsigned short* lB, f32x4 acc[4][4])
{
  int tid  = threadIdx.x;
  int wave = tid >> 6, lane = tid & 63, quad = lane >> 4, l16 = lane & 15;
  int m0 = blockIdx.y * 128, n0 = blockIdx.x * 128;
  int r0 = tid >> 2, kc = (tid & 3) * 8;             // 512 16B-chunks per tile
  const unsigned short* Ag = A  + (size_t)(m0 + r0) * 1024 + kc;
  const unsigned short* Bg = Bt + (size_t)(n0 + r0) * 1024 + kc;
  int wm = (wave >> 1) * 64, wn = (wave & 1) * 64;

  for (int k0 = 0; k0 < 1024; k0 += 32) {
    // async 16B-wide global->LDS staging (lds elem offset tid*8 == base wave*512 + lane*16B)
    gld16(Ag + k0,             lA + wave * 512);
    gld16(Ag + k0 + 64 * 1024, lA + 2048 + wave * 512);
    gld16(Bg + k0,             lB + wave * 512);
    gld16(Bg + k0 + 64 * 1024, lB + 2048 + wave * 512);
    __syncthreads();
    bf16x8 af[4], bfr[4];
#pragma unroll
    for (int i = 0; i < 4; i++) {
      af[i]  = *(const bf16x8*)&lA[(wm + i * 16 + l16) * 32 + quad * 8];
      bfr[i] = *(const bf16x8*)&lB[(wn + i * 16 + l16) * 32 + quad * 8];
    }
#pragma unroll
    for (int mi = 0; mi < 4; mi++)
#pragma unroll
      for (int ni = 0; ni < 4; ni++)
        acc[mi][ni] = __builtin_amdgcn_mfma_f32_16x16x32_bf16(af[mi], bfr[ni], acc[mi][ni], 0, 0, 0);
    __syncthreads();
  }
}

// ---------------- 9 projection GEMMs: P[s*3+w] = Xbf[s] @ W[w] + bias[w], bf16 out ----------------
__global__ __launch_bounds__(256, 2) void gemm_proj(
    const unsigned short* __restrict__ Xbf, const unsigned short* __restrict__ Wt,
    unsigned short* __restrict__ P,
    const float* __restrict__ bq, const float* __restrict__ bk, const float* __restrict__ bv)
{
  __shared__ alignas(16) unsigned short lA[128 * 32];
  __shared__ alignas(16) unsigned short lB[128 * 32];
  int z = blockIdx.z, s = z / 3, w = z - s * 3;
  const float* bias = (w == 0) ? bq : (w == 1) ? bk : bv;
  f32x4 acc[4][4];
#pragma unroll
  for (int i = 0; i < 4; i++)
#pragma unroll
    for (int j = 0; j < 4; j++) acc[i][j] = (f32x4){0.f, 0.f, 0.f, 0.f};
  gemm128_core(Xbf + (size_t)s * NTOK * 1024, Wt + (size_t)w * 1024 * 1024, lA, lB, acc);

  int tid = threadIdx.x, wave = tid >> 6, lane = tid & 63, quad = lane >> 4, l16 = lane & 15;
  int m0 = blockIdx.y * 128 + (wave >> 1) * 64;
  int n0 = blockIdx.x * 128 + (wave & 1) * 64;
  unsigned short* C = P + (size_t)z * NTOK * 1024;
#pragma unroll
  for (int mi = 0; mi < 4; mi++)
#pragma unroll
    for (int ni = 0; ni < 4; ni++) {
      int col = n0 + ni * 16 + l16;
      float bcol = bias[col];
#pragma unroll
      for (int r = 0; r < 4; r++) {
        int row = m0 + mi * 16 + quad * 4 + r;
        C[(size_t)row * 1024 + col] = f2bf(acc[mi][ni][r] + bcol);
      }
    }
}

// ---------------- V transpose: P[s*3+2] (tok x (h*64+d)) -> Vt[(s,b,h)] (64d x 1024l) ----------------
__global__ void transpose_v(const unsigned short* __restrict__ P, unsigned short* __restrict__ Vt) {
  __shared__ unsigned short t[64][65];
  int z = blockIdx.z;                 // s*128 + b*16 + h
  int s = z >> 7, bh = z & 127, h = bh & 15, b = bh >> 4;
  int l0 = blockIdx.x * 64;
  const unsigned short* src = P + (size_t)(s * 3 + 2) * NTOK * 1024
                                + (size_t)b * 1024 * 1024 + h * 64;
#pragma unroll
  for (int i = 0; i < 64; i += 8)
    t[threadIdx.y + i][threadIdx.x] = src[(size_t)(l0 + threadIdx.y + i) * 1024 + threadIdx.x];
  __syncthreads();
  unsigned short* dst = Vt + (size_t)z * 65536;   // [d][l], row stride 1024
#pragma unroll
  for (int i = 0; i < 64; i += 8)
    dst[(size_t)(threadIdx.y + i) * 1024 + l0 + threadIdx.x] = t[threadIdx.x][threadIdx.y + i];
}

// ---------------- fused dual attention v2: block-cooperative LDS staging ----------------
// block = 4 waves, 128 queries; K-loop stages 64 keys of K1,K2,Vt into LDS (shared)
__global__ __launch_bounds__(256, 4) void attn(
    const unsigned short* __restrict__ P, const unsigned short* __restrict__ Vt,
    unsigned short* __restrict__ Oa)
{
  __shared__ alignas(16) unsigned short lK1[64 * 64];   // [key][64d]
  __shared__ alignas(16) unsigned short lK2[64 * 64];   // [key][64d]
  __shared__ alignas(16) unsigned short lV [64 * 64];   // [d][64key]
  __shared__ alignas(16) unsigned short pls[4][32 * 32];// per-wave P relayout
  int o  = blockIdx.z;
  int As = (o == 0) ? 1 : 0;          // first (q,k) source stream
  int Bs = (o == 2) ? 1 : 2;          // second (q,k) source stream
  int b = blockIdx.y >> 4, h = blockIdx.y & 15;
  int tid = threadIdx.x, wave = tid >> 6, lane = tid & 63, quad = lane >> 4, l16 = lane & 15;
  int q0 = blockIdx.x * 128 + wave * 32;
  size_t bh_off = (size_t)b * 1024 * 1024 + h * 64;
  const unsigned short* Q1 = P + (size_t)(As * 3 + 0) * NTOK * 1024 + bh_off;
  const unsigned short* K1 = P + (size_t)(As * 3 + 1) * NTOK * 1024 + bh_off;
  const unsigned short* Q2 = P + (size_t)(Bs * 3 + 0) * NTOK * 1024 + bh_off;
  const unsigned short* K2 = P + (size_t)(Bs * 3 + 1) * NTOK * 1024 + bh_off;
  const unsigned short* V  = Vt + (size_t)((o * 8 + b) * 16 + h) * 65536;
  unsigned short* myp = pls[wave];

  // Q fragments: 2 q-tiles x 2 K-chunks, both score matrices
  bf16x8 q1f[2][2], q2f[2][2];
#pragma unroll
  for (int qt = 0; qt < 2; qt++)
#pragma unroll
    for (int c = 0; c < 2; c++) {
      q1f[qt][c] = *(const bf16x8*)&Q1[(size_t)(q0 + qt * 16 + l16) * 1024 + c * 32 + quad * 8];
      q2f[qt][c] = *(const bf16x8*)&Q2[(size_t)(q0 + qt * 16 + l16) * 1024 + c * 32 + quad * 8];
    }
  bf16x8 ones;
#pragma unroll
  for (int j = 0; j < 8; j++) ones[j] = (__bf16)1.0f;

  // staging source pointers: this lane handles row (wave*16 + lane/8), 16B chunk lane%8
  int srow = wave * 16 + (lane >> 3);
  int schk = (lane & 7) * 8;
  const unsigned short* K1s = K1 + (size_t)srow * 1024 + schk;  // row = key
  const unsigned short* K2s = K2 + (size_t)srow * 1024 + schk;
  const unsigned short* Vs  = V  + (size_t)srow * 1024 + schk;  // row = d, chunk = key

  f32x4 oacc[2][4];
#pragma unroll
  for (int qt = 0; qt < 2; qt++)
#pragma unroll
    for (int dt = 0; dt < 4; dt++) oacc[qt][dt] = (f32x4){0.f, 0.f, 0.f, 0.f};
  f32x4 lsum[2];
  lsum[0] = (f32x4){0.f, 0.f, 0.f, 0.f};
  lsum[1] = (f32x4){0.f, 0.f, 0.f, 0.f};

  for (int k0 = 0; k0 < 1024; k0 += 64) {
#pragma unroll
    for (int half = 0; half < 2; half++) {
      size_t krow = (size_t)(k0 + half * 8) * 1024;
      gld16(K1s + krow,                 lK1 + (wave * 16 + half * 8) * 64);
      gld16(K2s + krow,                 lK2 + (wave * 16 + half * 8) * 64);
      gld16(Vs + k0 + half * 8 * 1024,  lV  + (wave * 16 + half * 8) * 64);
    }
    __syncthreads();

#pragma unroll
    for (int kc = 0; kc < 2; kc++) {              // 32-key halves of the 64-key stage
      f32x4 sacc[2][2];
      sacc[0][0] = (f32x4){0.f, 0.f, 0.f, 0.f};
      sacc[0][1] = (f32x4){0.f, 0.f, 0.f, 0.f};
      sacc[1][0] = (f32x4){0.f, 0.f, 0.f, 0.f};
      sacc[1][1] = (f32x4){0.f, 0.f, 0.f, 0.f};
#pragma unroll
      for (int kt = 0; kt < 2; kt++) {
        int krow = (kc * 32 + kt * 16 + l16) * 64;
        bf16x8 k1a = *(const bf16x8*)&lK1[krow + quad * 8];
        bf16x8 k1b = *(const bf16x8*)&lK1[krow + 32 + quad * 8];
        bf16x8 k2a = *(const bf16x8*)&lK2[krow + quad * 8];
        bf16x8 k2b = *(const bf16x8*)&lK2[krow + 32 + quad * 8];
#pragma unroll
        for (int qt = 0; qt < 2; qt++) {
          sacc[qt][kt] = __builtin_amdgcn_mfma_f32_16x16x32_bf16(q1f[qt][0], k1a, sacc[qt][kt], 0, 0, 0);
          sacc[qt][kt] = __builtin_amdgcn_mfma_f32_16x16x32_bf16(q1f[qt][1], k1b, sacc[qt][kt], 0, 0, 0);
          sacc[qt][kt] = __builtin_amdgcn_mfma_f32_16x16x32_bf16(q2f[qt][0], k2a, sacc[qt][kt], 0, 0, 0);
          sacc[qt][kt] = __builtin_amdgcn_mfma_f32_16x16x32_bf16(q2f[qt][1], k2b, sacc[qt][kt], 0, 0, 0);
        }
      }
      // exp -> per-wave LDS (C-layout), read back as A-operand fragments
#pragma unroll
      for (int qt = 0; qt < 2; qt++)
#pragma unroll
        for (int kt = 0; kt < 2; kt++)
#pragma unroll
          for (int r = 0; r < 4; r++) {
            float p = __expf(sacc[qt][kt][r] * 0.0625f);  // scale = 1/sqrt(64)*0.5
            myp[(qt * 16 + quad * 4 + r) * 32 + kt * 16 + l16] = f2bf(p);
          }
      bf16x8 pa0 = *(const bf16x8*)&myp[l16 * 32 + quad * 8];
      bf16x8 pa1 = *(const bf16x8*)&myp[(16 + l16) * 32 + quad * 8];
      lsum[0] = __builtin_amdgcn_mfma_f32_16x16x32_bf16(pa0, ones, lsum[0], 0, 0, 0);
      lsum[1] = __builtin_amdgcn_mfma_f32_16x16x32_bf16(pa1, ones, lsum[1], 0, 0, 0);
#pragma unroll
      for (int dt = 0; dt < 4; dt++) {
        bf16x8 vf = *(const bf16x8*)&lV[(dt * 16 + l16) * 64 + kc * 32 + quad * 8];
        oacc[0][dt] = __builtin_amdgcn_mfma_f32_16x16x32_bf16(pa0, vf, oacc[0][dt], 0, 0, 0);
        oacc[1][dt] = __builtin_amdgcn_mfma_f32_16x16x32_bf16(pa1, vf, oacc[1][dt], 0, 0, 0);
      }
    }
    __syncthreads();
  }

  unsigned short* Od = Oa + (size_t)o * NTOK * 1024 + bh_off;
#pragma unroll
  for (int qt = 0; qt < 2; qt++)
#pragma unroll
    for (int dt = 0; dt < 4; dt++)
#pragma unroll
      for (int r = 0; r < 4; r++) {
        float val = oacc[qt][dt][r] / lsum[qt][r];
        Od[(size_t)(q0 + qt * 16 + quad * 4 + r) * 1024 + dt * 16 + l16] = f2bf(val);
      }
}

// ---------------- output GEMM: d_out[tok][s][:] = Oa[s] @ Wo + bo (fp32) ----------------
__global__ __launch_bounds__(256, 2) void gemm_out(
    const unsigned short* __restrict__ Oattn, const unsigned short* __restrict__ WtO,
    float* __restrict__ out, const float* __restrict__ bo)
{
  __shared__ alignas(16) unsigned short lA[128 * 32];
  __shared__ alignas(16) unsigned short lB[128 * 32];
  int s = blockIdx.z;
  f32x4 acc[4][4];
#pragma unroll
  for (int i = 0; i < 4; i++)
#pragma unroll
    for (int j = 0; j < 4; j++) acc[i][j] = (f32x4){0.f, 0.f, 0.f, 0.f};
  gemm128_core(Oattn + (size_t)s * NTOK * 1024, WtO, lA, lB, acc);

  int tid = threadIdx.x, wave = tid >> 6, lane = tid & 63, quad = lane >> 4, l16 = lane & 15;
  int m0 = blockIdx.y * 128 + (wave >> 1) * 64;
  int n0 = blockIdx.x * 128 + (wave & 1) * 64;
#pragma unroll
  for (int mi = 0; mi < 4; mi++)
#pragma unroll
    for (int ni = 0; ni < 4; ni++) {
      int col = n0 + ni * 16 + l16;
      float bcol = bo[col];
#pragma unroll
      for (int r = 0; r < 4; r++) {
        int row = m0 + mi * 16 + quad * 4 + r;
        out[(size_t)row * 3072 + s * 1024 + col] = acc[mi][ni][r] + bcol;
      }
    }
}

extern "C" void kernel_launch(void* const* d_in, const int* in_sizes, int n_in,
                              void* d_out, int out_size, void* d_ws, size_t ws_size,
                              hipStream_t stream) {
  (void)in_sizes; (void)n_in; (void)out_size; (void)ws_size;
  const float* x  = (const float*)d_in[0];
  const float* Wq = (const float*)d_in[1];
  const float* bq = (const float*)d_in[2];
  const float* Wk = (const float*)d_in[3];
  const float* bk = (const float*)d_in[4];
  const float* Wv = (const float*)d_in[5];
  const float* bv = (const float*)d_in[6];
  const float* Wo = (const float*)d_in[7];
  const float* bo = (const float*)d_in[8];
  float* out = (float*)d_out;

  char* ws = (char*)d_ws;
  // layout (bytes): Xbf 48MB (aliased by Vt after proj) | Wt 8MB | P 144MB | Oa 48MB
  unsigned short* Xbf = (unsigned short*)(ws + 0);
  unsigned short* Vt  = (unsigned short*)(ws + 0);          // alias: Xbf dead after gemm_proj
  unsigned short* Wt  = (unsigned short*)(ws + 50331648);
  unsigned short* P   = (unsigned short*)(ws + 58720256);
  unsigned short* Oa  = (unsigned short*)(ws + 209715200);

  convert_x<<<24576, 256, 0, stream>>>(x, Xbf);
  dim3 tb(32, 8), tg(32, 32);
  transpose_w<<<tg, tb, 0, stream>>>(Wq, Wt + 0 * 1048576);
  transpose_w<<<tg, tb, 0, stream>>>(Wk, Wt + 1 * 1048576);
  transpose_w<<<tg, tb, 0, stream>>>(Wv, Wt + 2 * 1048576);
  transpose_w<<<tg, tb, 0, stream>>>(Wo, Wt + 3 * 1048576);

  gemm_proj<<<dim3(8, 64, 9), 256, 0, stream>>>(Xbf, Wt, P, bq, bk, bv);
  transpose_v<<<dim3(16, 1, 384), dim3(64, 8), 0, stream>>>(P, Vt);
  attn<<<dim3(8, 128, 3), 256, 0, stream>>>(P, Vt, Oa);
  gemm_out<<<dim3(8, 64, 3), 256, 0, stream>>>(Oa, Wt + 3 * 1048576, out, bo);
}

// Round 3
// 685.198 us; speedup vs baseline: 2.2620x; 1.0582x over previous
//
#include <hip/hip_runtime.h>
#include <hip/hip_bf16.h>
#include <stdint.h>

#define NTOK 8192          // B*L = 8*1024
#define DM   1024

typedef __bf16 bf16x8 __attribute__((ext_vector_type(8)));
typedef float  f32x4  __attribute__((ext_vector_type(4)));

__device__ __forceinline__ unsigned short f2bf(float f) {
  union { float f; unsigned u; } v; v.f = f;
  unsigned r = v.u + 0x7FFFu + ((v.u >> 16) & 1u);   // round-to-nearest-even
  return (unsigned short)(r >> 16);
}

// async global->LDS, 16B per lane; LDS dest = wave-uniform base + lane*16
__device__ __forceinline__ void gld16(const void* g, const void* l) {
  __builtin_amdgcn_global_load_lds(
      (const __attribute__((address_space(1))) uint32_t*)g,
      (__attribute__((address_space(3))) uint32_t*)l, 16, 0, 0);
}

// ---------------- convert x: fp32 [tok][3][1024] -> bf16 [s][tok][1024] ----------------
__global__ void convert_x(const float* __restrict__ x, unsigned short* __restrict__ Xbf) {
  int idx = (blockIdx.x * 256 + threadIdx.x) * 4;
  int s   = idx >> 23;
  int rem = idx & ((1 << 23) - 1);
  int tok = rem >> 10;
  int d   = rem & 1023;
  const float4 v = *(const float4*)&x[((size_t)tok * 3 + s) * 1024 + d];
  ushort4 o;
  o.x = f2bf(v.x); o.y = f2bf(v.y); o.z = f2bf(v.z); o.w = f2bf(v.w);
  *(ushort4*)&Xbf[idx] = o;
}

// ---------------- W (K x N fp32) -> Wt (N x K bf16), 1024x1024 ----------------
__global__ void transpose_w(const float* __restrict__ W, unsigned short* __restrict__ Wt) {
  __shared__ float t[32][33];
  int tx = threadIdx.x, ty = threadIdx.y;            // block (32,8)
  int bx = blockIdx.x * 32, by = blockIdx.y * 32;
#pragma unroll
  for (int i = 0; i < 32; i += 8)
    t[ty + i][tx] = W[(size_t)(by + ty + i) * 1024 + bx + tx];
  __syncthreads();
#pragma unroll
  for (int i = 0; i < 32; i += 8)
    Wt[(size_t)(bx + ty + i) * 1024 + by + tx] = f2bf(t[tx][ty + i]);  // Wt[n][k]=W[k][n]
}

// ---------------- shared 128x128 GEMM core, A: Mx1024 bf16, Bt: Nx1024 bf16 ----------------
// LDS tiles XOR-swizzled: 16B chunk c of row r stored at physical chunk c^(r&3)
__device__ __forceinline__ void gemm128_core(
    const unsigned short* __restrict__ A, const unsigned short* __restrict__ Bt,
    unsigned short* lA, unsigned short* lB, f32x4 acc[4][4])
{
  int tid  = threadIdx.x;
  int wave = tid >> 6, lane = tid & 63, quad = lane >> 4, l16 = lane & 15;
  int m0 = blockIdx.y * 128, n0 = blockIdx.x * 128;
  int r0 = tid >> 2;
  int kc = (((tid & 3) ^ (r0 & 3)) * 8);             // XOR source swizzle (16B units)
  const unsigned short* Ag = A  + (size_t)(m0 + r0) * 1024 + kc;
  const unsigned short* Bg = Bt + (size_t)(n0 + r0) * 1024 + kc;
  int wm = (wave >> 1) * 64, wn = (wave & 1) * 64;
  int fsw = (l16 & 3);                               // fragment-read swizzle key

  for (int k0 = 0; k0 < 1024; k0 += 32) {
    gld16(Ag + k0,             lA + wave * 512);
    gld16(Ag + k0 + 64 * 1024, lA + 2048 + wave * 512);
    gld16(Bg + k0,             lB + wave * 512);
    gld16(Bg + k0 + 64 * 1024, lB + 2048 + wave * 512);
    __syncthreads();
    bf16x8 af[4], bfr[4];
    int fo = ((quad ^ fsw) * 8);
#pragma unroll
    for (int i = 0; i < 4; i++) {
      af[i]  = *(const bf16x8*)&lA[(wm + i * 16 + l16) * 32 + fo];
      bfr[i] = *(const bf16x8*)&lB[(wn + i * 16 + l16) * 32 + fo];
    }
#pragma unroll
    for (int mi = 0; mi < 4; mi++)
#pragma unroll
      for (int ni = 0; ni < 4; ni++)
        acc[mi][ni] = __builtin_amdgcn_mfma_f32_16x16x32_bf16(af[mi], bfr[ni], acc[mi][ni], 0, 0, 0);
    __syncthreads();
  }
}

// ---------------- 9 projection GEMMs: P[s*3+w] = Xbf[s] @ W[w] + bias[w], bf16 out ----------------
__global__ __launch_bounds__(256, 2) void gemm_proj(
    const unsigned short* __restrict__ Xbf, const unsigned short* __restrict__ Wt,
    unsigned short* __restrict__ P,
    const float* __restrict__ bq, const float* __restrict__ bk, const float* __restrict__ bv)
{
  __shared__ alignas(16) unsigned short lA[128 * 32];
  __shared__ alignas(16) unsigned short lB[128 * 32];
  int z = blockIdx.z, s = z / 3, w = z - s * 3;
  const float* bias = (w == 0) ? bq : (w == 1) ? bk : bv;
  f32x4 acc[4][4];
#pragma unroll
  for (int i = 0; i < 4; i++)
#pragma unroll
    for (int j = 0; j < 4; j++) acc[i][j] = (f32x4){0.f, 0.f, 0.f, 0.f};
  gemm128_core(Xbf + (size_t)s * NTOK * 1024, Wt + (size_t)w * 1024 * 1024, lA, lB, acc);

  int tid = threadIdx.x, wave = tid >> 6, lane = tid & 63, quad = lane >> 4, l16 = lane & 15;
  int m0 = blockIdx.y * 128 + (wave >> 1) * 64;
  int n0 = blockIdx.x * 128 + (wave & 1) * 64;
  unsigned short* C = P + (size_t)z * NTOK * 1024;
#pragma unroll
  for (int mi = 0; mi < 4; mi++)
#pragma unroll
    for (int ni = 0; ni < 4; ni++) {
      int col = n0 + ni * 16 + l16;
      float bcol = bias[col];
#pragma unroll
      for (int r = 0; r < 4; r++) {
        int row = m0 + mi * 16 + quad * 4 + r;
        C[(size_t)row * 1024 + col] = f2bf(acc[mi][ni][r] + bcol);
      }
    }
}

// ---------------- V transpose: P[s*3+2] (tok x (h*64+d)) -> Vt[(s,b,h)] (64d x 1024l) ----------------
__global__ void transpose_v(const unsigned short* __restrict__ P, unsigned short* __restrict__ Vt) {
  __shared__ unsigned short t[64][65];
  int z = blockIdx.z;                 // s*128 + b*16 + h
  int s = z >> 7, bh = z & 127, h = bh & 15, b = bh >> 4;
  int l0 = blockIdx.x * 64;
  const unsigned short* src = P + (size_t)(s * 3 + 2) * NTOK * 1024
                                + (size_t)b * 1024 * 1024 + h * 64;
#pragma unroll
  for (int i = 0; i < 64; i += 8)
    t[threadIdx.y + i][threadIdx.x] = src[(size_t)(l0 + threadIdx.y + i) * 1024 + threadIdx.x];
  __syncthreads();
  unsigned short* dst = Vt + (size_t)z * 65536;   // [d][l], row stride 1024
#pragma unroll
  for (int i = 0; i < 64; i += 8)
    dst[(size_t)(threadIdx.y + i) * 1024 + l0 + threadIdx.x] = t[threadIdx.x][threadIdx.y + i];
}

// ---------------- fused dual attention v3: swizzled staging, padded P-relayout ----------------
__global__ __launch_bounds__(256, 4) void attn(
    const unsigned short* __restrict__ P, const unsigned short* __restrict__ Vt,
    unsigned short* __restrict__ Oa)
{
  __shared__ alignas(16) unsigned short lK1[64 * 64];   // [key][8 x 16B chunks, XOR-swizzled]
  __shared__ alignas(16) unsigned short lK2[64 * 64];
  __shared__ alignas(16) unsigned short lV [64 * 64];   // [d][8 chunks of keys, XOR-swizzled]
  __shared__ alignas(16) unsigned short pls[4][32 * 40];// per-wave P relayout, 80B rows
  int o  = blockIdx.z;
  int As = (o == 0) ? 1 : 0;          // first (q,k) source stream
  int Bs = (o == 2) ? 1 : 2;          // second (q,k) source stream
  int b = blockIdx.y >> 4, h = blockIdx.y & 15;
  int tid = threadIdx.x, wave = tid >> 6, lane = tid & 63, quad = lane >> 4, l16 = lane & 15;
  int q0 = blockIdx.x * 128 + wave * 32;
  size_t bh_off = (size_t)b * 1024 * 1024 + h * 64;
  const unsigned short* Q1 = P + (size_t)(As * 3 + 0) * NTOK * 1024 + bh_off;
  const unsigned short* K1 = P + (size_t)(As * 3 + 1) * NTOK * 1024 + bh_off;
  const unsigned short* Q2 = P + (size_t)(Bs * 3 + 0) * NTOK * 1024 + bh_off;
  const unsigned short* K2 = P + (size_t)(Bs * 3 + 1) * NTOK * 1024 + bh_off;
  const unsigned short* V  = Vt + (size_t)((o * 8 + b) * 16 + h) * 65536;
  unsigned short* myp = pls[wave];

  bf16x8 q1f[2][2], q2f[2][2];
#pragma unroll
  for (int qt = 0; qt < 2; qt++)
#pragma unroll
    for (int c = 0; c < 2; c++) {
      q1f[qt][c] = *(const bf16x8*)&Q1[(size_t)(q0 + qt * 16 + l16) * 1024 + c * 32 + quad * 8];
      q2f[qt][c] = *(const bf16x8*)&Q2[(size_t)(q0 + qt * 16 + l16) * 1024 + c * 32 + quad * 8];
    }
  bf16x8 ones;
#pragma unroll
  for (int j = 0; j < 8; j++) ones[j] = (__bf16)1.0f;

  // staging: lane covers row (wave*16 + lane/8), swizzled 16B chunk (lane%8)^(row%8)
  int r8 = lane >> 3;
  int cs = ((lane & 7) ^ r8) * 8;                      // XOR source swizzle
  int srow = wave * 16 + r8;
  const unsigned short* K1s = K1 + (size_t)srow * 1024 + cs;
  const unsigned short* K2s = K2 + (size_t)srow * 1024 + cs;
  const unsigned short* Vs  = V  + (size_t)srow * 1024 + cs;
  int fsw = (l16 & 7);                                 // fragment-read swizzle key

  f32x4 oacc[2][4];
#pragma unroll
  for (int qt = 0; qt < 2; qt++)
#pragma unroll
    for (int dt = 0; dt < 4; dt++) oacc[qt][dt] = (f32x4){0.f, 0.f, 0.f, 0.f};
  f32x4 lsum[2];
  lsum[0] = (f32x4){0.f, 0.f, 0.f, 0.f};
  lsum[1] = (f32x4){0.f, 0.f, 0.f, 0.f};

  const float SC = 0.09016844136867f;  // (1/sqrt(64))*0.5*log2(e)

  for (int k0 = 0; k0 < 1024; k0 += 64) {
#pragma unroll
    for (int half = 0; half < 2; half++) {
      size_t krow = (size_t)(k0 + half * 8) * 1024;
      gld16(K1s + krow,                 lK1 + (wave * 16 + half * 8) * 64);
      gld16(K2s + krow,                 lK2 + (wave * 16 + half * 8) * 64);
      gld16(Vs + k0 + half * 8 * 1024,  lV  + (wave * 16 + half * 8) * 64);
    }
    __syncthreads();

#pragma unroll
    for (int kc = 0; kc < 2; kc++) {              // 32-key halves of the 64-key stage
      f32x4 sacc[2][2];
      sacc[0][0] = (f32x4){0.f, 0.f, 0.f, 0.f};
      sacc[0][1] = (f32x4){0.f, 0.f, 0.f, 0.f};
      sacc[1][0] = (f32x4){0.f, 0.f, 0.f, 0.f};
      sacc[1][1] = (f32x4){0.f, 0.f, 0.f, 0.f};
#pragma unroll
      for (int kt = 0; kt < 2; kt++) {
        int krow = (kc * 32 + kt * 16 + l16) * 64;
        bf16x8 k1a = *(const bf16x8*)&lK1[krow + ((quad ^ fsw) * 8)];
        bf16x8 k1b = *(const bf16x8*)&lK1[krow + (((quad + 4) ^ fsw) * 8)];
        bf16x8 k2a = *(const bf16x8*)&lK2[krow + ((quad ^ fsw) * 8)];
        bf16x8 k2b = *(const bf16x8*)&lK2[krow + (((quad + 4) ^ fsw) * 8)];
#pragma unroll
        for (int qt = 0; qt < 2; qt++) {
          sacc[qt][kt] = __builtin_amdgcn_mfma_f32_16x16x32_bf16(q1f[qt][0], k1a, sacc[qt][kt], 0, 0, 0);
          sacc[qt][kt] = __builtin_amdgcn_mfma_f32_16x16x32_bf16(q1f[qt][1], k1b, sacc[qt][kt], 0, 0, 0);
          sacc[qt][kt] = __builtin_amdgcn_mfma_f32_16x16x32_bf16(q2f[qt][0], k2a, sacc[qt][kt], 0, 0, 0);
          sacc[qt][kt] = __builtin_amdgcn_mfma_f32_16x16x32_bf16(q2f[qt][1], k2b, sacc[qt][kt], 0, 0, 0);
        }
      }
      // exp2 -> bf16 pair-pack (round-half-up) -> padded per-wave LDS, read back A-layout
#pragma unroll
      for (int qt = 0; qt < 2; qt++)
#pragma unroll
        for (int kt = 0; kt < 2; kt++)
#pragma unroll
          for (int r2 = 0; r2 < 2; r2++) {
            union { float f; unsigned u; } e0, e1;
            e0.f = __builtin_amdgcn_exp2f(sacc[qt][kt][r2 * 2]     * SC);
            e1.f = __builtin_amdgcn_exp2f(sacc[qt][kt][r2 * 2 + 1] * SC);
            unsigned pk = __builtin_amdgcn_perm(e1.u + 0x8000u, e0.u + 0x8000u, 0x07060302u);
            int row = qt * 16 + quad * 4 + r2 * 2;
            myp[row * 40 + kt * 16 + l16]       = (unsigned short)pk;
            myp[(row + 1) * 40 + kt * 16 + l16] = (unsigned short)(pk >> 16);
          }
      bf16x8 pa0 = *(const bf16x8*)&myp[l16 * 40 + quad * 8];
      bf16x8 pa1 = *(const bf16x8*)&myp[(16 + l16) * 40 + quad * 8];
      lsum[0] = __builtin_amdgcn_mfma_f32_16x16x32_bf16(pa0, ones, lsum[0], 0, 0, 0);
      lsum[1] = __builtin_amdgcn_mfma_f32_16x16x32_bf16(pa1, ones, lsum[1], 0, 0, 0);
#pragma unroll
      for (int dt = 0; dt < 4; dt++) {
        bf16x8 vf = *(const bf16x8*)&lV[(dt * 16 + l16) * 64 + (((kc * 4 + quad) ^ fsw) * 8)];
        oacc[0][dt] = __builtin_amdgcn_mfma_f32_16x16x32_bf16(pa0, vf, oacc[0][dt], 0, 0, 0);
        oacc[1][dt] = __builtin_amdgcn_mfma_f32_16x16x32_bf16(pa1, vf, oacc[1][dt], 0, 0, 0);
      }
    }
    __syncthreads();
  }

  unsigned short* Od = Oa + (size_t)o * NTOK * 1024 + bh_off;
#pragma unroll
  for (int qt = 0; qt < 2; qt++)
#pragma unroll
    for (int dt = 0; dt < 4; dt++)
#pragma unroll
      for (int r = 0; r < 4; r++) {
        float val = oacc[qt][dt][r] / lsum[qt][r];
        Od[(size_t)(q0 + qt * 16 + quad * 4 + r) * 1024 + dt * 16 + l16] = f2bf(val);
      }
}

// ---------------- output GEMM: d_out[tok][s][:] = Oa[s] @ Wo + bo (fp32) ----------------
__global__ __launch_bounds__(256, 2) void gemm_out(
    const unsigned short* __restrict__ Oattn, const unsigned short* __restrict__ WtO,
    float* __restrict__ out, const float* __restrict__ bo)
{
  __shared__ alignas(16) unsigned short lA[128 * 32];
  __shared__ alignas(16) unsigned short lB[128 * 32];
  int s = blockIdx.z;
  f32x4 acc[4][4];
#pragma unroll
  for (int i = 0; i < 4; i++)
#pragma unroll
    for (int j = 0; j < 4; j++) acc[i][j] = (f32x4){0.f, 0.f, 0.f, 0.f};
  gemm128_core(Oattn + (size_t)s * NTOK * 1024, WtO, lA, lB, acc);

  int tid = threadIdx.x, wave = tid >> 6, lane = tid & 63, quad = lane >> 4, l16 = lane & 15;
  int m0 = blockIdx.y * 128 + (wave >> 1) * 64;
  int n0 = blockIdx.x * 128 + (wave & 1) * 64;
#pragma unroll
  for (int mi = 0; mi < 4; mi++)
#pragma unroll
    for (int ni = 0; ni < 4; ni++) {
      int col = n0 + ni * 16 + l16;
      float bcol = bo[col];
#pragma unroll
      for (int r = 0; r < 4; r++) {
        int row = m0 + mi * 16 + quad * 4 + r;
        out[(size_t)row * 3072 + s * 1024 + col] = acc[mi][ni][r] + bcol;
      }
    }
}

extern "C" void kernel_launch(void* const* d_in, const int* in_sizes, int n_in,
                              void* d_out, int out_size, void* d_ws, size_t ws_size,
                              hipStream_t stream) {
  (void)in_sizes; (void)n_in; (void)out_size; (void)ws_size;
  const float* x  = (const float*)d_in[0];
  const float* Wq = (const float*)d_in[1];
  const float* bq = (const float*)d_in[2];
  const float* Wk = (const float*)d_in[3];
  const float* bk = (const float*)d_in[4];
  const float* Wv = (const float*)d_in[5];
  const float* bv = (const float*)d_in[6];
  const float* Wo = (const float*)d_in[7];
  const float* bo = (const float*)d_in[8];
  float* out = (float*)d_out;

  char* ws = (char*)d_ws;
  // layout (bytes): Xbf 48MB (aliased by Vt after proj) | Wt 8MB | P 144MB | Oa 48MB
  unsigned short* Xbf = (unsigned short*)(ws + 0);
  unsigned short* Vt  = (unsigned short*)(ws + 0);          // alias: Xbf dead after gemm_proj
  unsigned short* Wt  = (unsigned short*)(ws + 50331648);
  unsigned short* P   = (unsigned short*)(ws + 58720256);
  unsigned short* Oa  = (unsigned short*)(ws + 209715200);

  convert_x<<<24576, 256, 0, stream>>>(x, Xbf);
  dim3 tb(32, 8), tg(32, 32);
  transpose_w<<<tg, tb, 0, stream>>>(Wq, Wt + 0 * 1048576);
  transpose_w<<<tg, tb, 0, stream>>>(Wk, Wt + 1 * 1048576);
  transpose_w<<<tg, tb, 0, stream>>>(Wv, Wt + 2 * 1048576);
  transpose_w<<<tg, tb, 0, stream>>>(Wo, Wt + 3 * 1048576);

  gemm_proj<<<dim3(8, 64, 9), 256, 0, stream>>>(Xbf, Wt, P, bq, bk, bv);
  transpose_v<<<dim3(16, 1, 384), dim3(64, 8), 0, stream>>>(P, Vt);
  attn<<<dim3(8, 128, 3), 256, 0, stream>>>(P, Vt, Oa);
  gemm_out<<<dim3(8, 64, 3), 256, 0, stream>>>(Oa, Wt + 3 * 1048576, out, bo);
}

// Round 4
// 643.660 us; speedup vs baseline: 2.4080x; 1.0645x over previous
//
#include <hip/hip_runtime.h>
#include <hip/hip_bf16.h>
#include <stdint.h>

#define NTOK 8192          // B*L = 8*1024
#define DM   1024

typedef __bf16 bf16x8 __attribute__((ext_vector_type(8)));
typedef float  f32x4  __attribute__((ext_vector_type(4)));

__device__ __forceinline__ unsigned short f2bf(float f) {
  union { float f; unsigned u; } v; v.f = f;
  unsigned r = v.u + 0x7FFFu + ((v.u >> 16) & 1u);   // round-to-nearest-even
  return (unsigned short)(r >> 16);
}

// async global->LDS, 16B per lane; LDS dest = wave-uniform base + lane*16
__device__ __forceinline__ void gld16(const void* g, const void* l) {
  __builtin_amdgcn_global_load_lds(
      (const __attribute__((address_space(1))) uint32_t*)g,
      (__attribute__((address_space(3))) uint32_t*)l, 16, 0, 0);
}

// ---------------- convert x: fp32 [tok][3][1024] -> bf16 [s][tok][1024] ----------------
__global__ void convert_x(const float* __restrict__ x, unsigned short* __restrict__ Xbf) {
  int idx = (blockIdx.x * 256 + threadIdx.x) * 4;
  int s   = idx >> 23;
  int rem = idx & ((1 << 23) - 1);
  int tok = rem >> 10;
  int d   = rem & 1023;
  const float4 v = *(const float4*)&x[((size_t)tok * 3 + s) * 1024 + d];
  ushort4 o;
  o.x = f2bf(v.x); o.y = f2bf(v.y); o.z = f2bf(v.z); o.w = f2bf(v.w);
  *(ushort4*)&Xbf[idx] = o;
}

// ---------------- W (K x N fp32) -> Wt (N x K bf16), 1024x1024 ----------------
__global__ void transpose_w(const float* __restrict__ W, unsigned short* __restrict__ Wt) {
  __shared__ float t[32][33];
  int tx = threadIdx.x, ty = threadIdx.y;            // block (32,8)
  int bx = blockIdx.x * 32, by = blockIdx.y * 32;
#pragma unroll
  for (int i = 0; i < 32; i += 8)
    t[ty + i][tx] = W[(size_t)(by + ty + i) * 1024 + bx + tx];
  __syncthreads();
#pragma unroll
  for (int i = 0; i < 32; i += 8)
    Wt[(size_t)(bx + ty + i) * 1024 + by + tx] = f2bf(t[tx][ty + i]);  // Wt[n][k]=W[k][n]
}

// ---------------- shared 128x128 GEMM core, A: Mx1024 bf16, Bt: Nx1024 bf16 ----------------
// grid: x = m-block (so A-tile sharers land on the same XCD), y = n-block
// LDS tiles XOR-swizzled by (row>>1)&3 -> 8 bank-groups per quad -> 2-way (free)
__device__ __forceinline__ void gemm128_core(
    const unsigned short* __restrict__ A, const unsigned short* __restrict__ Bt,
    unsigned short* lA, unsigned short* lB, f32x4 acc[4][4])
{
  int tid  = threadIdx.x;
  int wave = tid >> 6, lane = tid & 63, quad = lane >> 4, l16 = lane & 15;
  int m0 = blockIdx.x * 128, n0 = blockIdx.y * 128;
  int r0 = tid >> 2;
  int kc = (((tid & 3) ^ ((tid >> 3) & 3)) * 8);     // XOR source swizzle, key (r0>>1)&3
  const unsigned short* Ag = A  + (size_t)(m0 + r0) * 1024 + kc;
  const unsigned short* Bg = Bt + (size_t)(n0 + r0) * 1024 + kc;
  int wm = (wave >> 1) * 64, wn = (wave & 1) * 64;
  int fsw = (l16 >> 1) & 3;                          // fragment-read swizzle key

  for (int k0 = 0; k0 < 1024; k0 += 32) {
    gld16(Ag + k0,             lA + wave * 512);
    gld16(Ag + k0 + 64 * 1024, lA + 2048 + wave * 512);
    gld16(Bg + k0,             lB + wave * 512);
    gld16(Bg + k0 + 64 * 1024, lB + 2048 + wave * 512);
    __syncthreads();
    bf16x8 af[4], bfr[4];
    int fo = ((quad ^ fsw) * 8);
#pragma unroll
    for (int i = 0; i < 4; i++) {
      af[i]  = *(const bf16x8*)&lA[(wm + i * 16 + l16) * 32 + fo];
      bfr[i] = *(const bf16x8*)&lB[(wn + i * 16 + l16) * 32 + fo];
    }
#pragma unroll
    for (int mi = 0; mi < 4; mi++)
#pragma unroll
      for (int ni = 0; ni < 4; ni++)
        acc[mi][ni] = __builtin_amdgcn_mfma_f32_16x16x32_bf16(af[mi], bfr[ni], acc[mi][ni], 0, 0, 0);
    __syncthreads();
  }
}

// ---------------- 9 projection GEMMs: P[s*3+w] = Xbf[s] @ W[w] + bias[w], bf16 out ----------------
__global__ __launch_bounds__(256, 2) void gemm_proj(
    const unsigned short* __restrict__ Xbf, const unsigned short* __restrict__ Wt,
    unsigned short* __restrict__ P,
    const float* __restrict__ bq, const float* __restrict__ bk, const float* __restrict__ bv)
{
  __shared__ alignas(16) unsigned short lA[128 * 32];
  __shared__ alignas(16) unsigned short lB[128 * 32];
  int z = blockIdx.z, s = z / 3, w = z - s * 3;
  const float* bias = (w == 0) ? bq : (w == 1) ? bk : bv;
  f32x4 acc[4][4];
#pragma unroll
  for (int i = 0; i < 4; i++)
#pragma unroll
    for (int j = 0; j < 4; j++) acc[i][j] = (f32x4){0.f, 0.f, 0.f, 0.f};
  gemm128_core(Xbf + (size_t)s * NTOK * 1024, Wt + (size_t)w * 1024 * 1024, lA, lB, acc);

  int tid = threadIdx.x, wave = tid >> 6, lane = tid & 63, quad = lane >> 4, l16 = lane & 15;
  int m0 = blockIdx.x * 128 + (wave >> 1) * 64;
  int n0 = blockIdx.y * 128 + (wave & 1) * 64;
  unsigned short* C = P + (size_t)z * NTOK * 1024;
#pragma unroll
  for (int mi = 0; mi < 4; mi++)
#pragma unroll
    for (int ni = 0; ni < 4; ni++) {
      int col = n0 + ni * 16 + l16;
      float bcol = bias[col];
#pragma unroll
      for (int r = 0; r < 4; r++) {
        int row = m0 + mi * 16 + quad * 4 + r;
        C[(size_t)row * 1024 + col] = f2bf(acc[mi][ni][r] + bcol);
      }
    }
}

// ---------------- V transpose: P[s*3+2] (tok x (h*64+d)) -> Vt[(s,b,h)] (64d x 1024l) ----------------
__global__ void transpose_v(const unsigned short* __restrict__ P, unsigned short* __restrict__ Vt) {
  __shared__ unsigned short t[64][65];
  int z = blockIdx.z;                 // s*128 + b*16 + h
  int s = z >> 7, bh = z & 127, h = bh & 15, b = bh >> 4;
  int l0 = blockIdx.x * 64;
  const unsigned short* src = P + (size_t)(s * 3 + 2) * NTOK * 1024
                                + (size_t)b * 1024 * 1024 + h * 64;
#pragma unroll
  for (int i = 0; i < 64; i += 8)
    t[threadIdx.y + i][threadIdx.x] = src[(size_t)(l0 + threadIdx.y + i) * 1024 + threadIdx.x];
  __syncthreads();
  unsigned short* dst = Vt + (size_t)z * 65536;   // [d][l], row stride 1024
#pragma unroll
  for (int i = 0; i < 64; i += 8)
    dst[(size_t)(threadIdx.y + i) * 1024 + l0 + threadIdx.x] = t[threadIdx.x][threadIdx.y + i];
}

// ---------------- fused dual attention v4: grid x=bh (K/V sharers on same XCD), y=q-block ----------------
__global__ __launch_bounds__(256, 4) void attn(
    const unsigned short* __restrict__ P, const unsigned short* __restrict__ Vt,
    unsigned short* __restrict__ Oa)
{
  __shared__ alignas(16) unsigned short lK1[64 * 64];   // [key][8 x 16B chunks, XOR-swizzled]
  __shared__ alignas(16) unsigned short lK2[64 * 64];
  __shared__ alignas(16) unsigned short lV [64 * 64];   // [d][8 chunks of keys, XOR-swizzled]
  __shared__ alignas(16) unsigned short pls[4][32 * 40];// per-wave P relayout, 80B rows
  int o  = blockIdx.z;
  int As = (o == 0) ? 1 : 0;          // first (q,k) source stream
  int Bs = (o == 2) ? 1 : 2;          // second (q,k) source stream
  int b = blockIdx.x >> 4, h = blockIdx.x & 15;
  int tid = threadIdx.x, wave = tid >> 6, lane = tid & 63, quad = lane >> 4, l16 = lane & 15;
  int q0 = blockIdx.y * 128 + wave * 32;
  size_t bh_off = (size_t)b * 1024 * 1024 + h * 64;
  const unsigned short* Q1 = P + (size_t)(As * 3 + 0) * NTOK * 1024 + bh_off;
  const unsigned short* K1 = P + (size_t)(As * 3 + 1) * NTOK * 1024 + bh_off;
  const unsigned short* Q2 = P + (size_t)(Bs * 3 + 0) * NTOK * 1024 + bh_off;
  const unsigned short* K2 = P + (size_t)(Bs * 3 + 1) * NTOK * 1024 + bh_off;
  const unsigned short* V  = Vt + (size_t)((o * 8 + b) * 16 + h) * 65536;
  unsigned short* myp = pls[wave];

  bf16x8 q1f[2][2], q2f[2][2];
#pragma unroll
  for (int qt = 0; qt < 2; qt++)
#pragma unroll
    for (int c = 0; c < 2; c++) {
      q1f[qt][c] = *(const bf16x8*)&Q1[(size_t)(q0 + qt * 16 + l16) * 1024 + c * 32 + quad * 8];
      q2f[qt][c] = *(const bf16x8*)&Q2[(size_t)(q0 + qt * 16 + l16) * 1024 + c * 32 + quad * 8];
    }
  bf16x8 ones;
#pragma unroll
  for (int j = 0; j < 8; j++) ones[j] = (__bf16)1.0f;

  // staging: lane covers row (wave*16 + lane/8), swizzled 16B chunk (lane%8)^(row%8)
  int r8 = lane >> 3;
  int cs = ((lane & 7) ^ r8) * 8;                      // XOR source swizzle
  int srow = wave * 16 + r8;
  const unsigned short* K1s = K1 + (size_t)srow * 1024 + cs;
  const unsigned short* K2s = K2 + (size_t)srow * 1024 + cs;
  const unsigned short* Vs  = V  + (size_t)srow * 1024 + cs;
  int fsw = (l16 & 7);                                 // fragment-read swizzle key

  f32x4 oacc[2][4];
#pragma unroll
  for (int qt = 0; qt < 2; qt++)
#pragma unroll
    for (int dt = 0; dt < 4; dt++) oacc[qt][dt] = (f32x4){0.f, 0.f, 0.f, 0.f};
  f32x4 lsum[2];
  lsum[0] = (f32x4){0.f, 0.f, 0.f, 0.f};
  lsum[1] = (f32x4){0.f, 0.f, 0.f, 0.f};

  const float SC = 0.09016844136867f;  // (1/sqrt(64))*0.5*log2(e)

  for (int k0 = 0; k0 < 1024; k0 += 64) {
#pragma unroll
    for (int half = 0; half < 2; half++) {
      size_t krow = (size_t)(k0 + half * 8) * 1024;
      gld16(K1s + krow,                 lK1 + (wave * 16 + half * 8) * 64);
      gld16(K2s + krow,                 lK2 + (wave * 16 + half * 8) * 64);
      gld16(Vs + k0 + half * 8 * 1024,  lV  + (wave * 16 + half * 8) * 64);
    }
    __syncthreads();

#pragma unroll
    for (int kc = 0; kc < 2; kc++) {              // 32-key halves of the 64-key stage
      f32x4 sacc[2][2];
      sacc[0][0] = (f32x4){0.f, 0.f, 0.f, 0.f};
      sacc[0][1] = (f32x4){0.f, 0.f, 0.f, 0.f};
      sacc[1][0] = (f32x4){0.f, 0.f, 0.f, 0.f};
      sacc[1][1] = (f32x4){0.f, 0.f, 0.f, 0.f};
#pragma unroll
      for (int kt = 0; kt < 2; kt++) {
        int krow = (kc * 32 + kt * 16 + l16) * 64;
        bf16x8 k1a = *(const bf16x8*)&lK1[krow + ((quad ^ fsw) * 8)];
        bf16x8 k1b = *(const bf16x8*)&lK1[krow + (((quad + 4) ^ fsw) * 8)];
        bf16x8 k2a = *(const bf16x8*)&lK2[krow + ((quad ^ fsw) * 8)];
        bf16x8 k2b = *(const bf16x8*)&lK2[krow + (((quad + 4) ^ fsw) * 8)];
#pragma unroll
        for (int qt = 0; qt < 2; qt++) {
          sacc[qt][kt] = __builtin_amdgcn_mfma_f32_16x16x32_bf16(q1f[qt][0], k1a, sacc[qt][kt], 0, 0, 0);
          sacc[qt][kt] = __builtin_amdgcn_mfma_f32_16x16x32_bf16(q1f[qt][1], k1b, sacc[qt][kt], 0, 0, 0);
          sacc[qt][kt] = __builtin_amdgcn_mfma_f32_16x16x32_bf16(q2f[qt][0], k2a, sacc[qt][kt], 0, 0, 0);
          sacc[qt][kt] = __builtin_amdgcn_mfma_f32_16x16x32_bf16(q2f[qt][1], k2b, sacc[qt][kt], 0, 0, 0);
        }
      }
      // exp2 -> bf16 pair-pack (round-half-up) -> padded per-wave LDS, read back A-layout
#pragma unroll
      for (int qt = 0; qt < 2; qt++)
#pragma unroll
        for (int kt = 0; kt < 2; kt++)
#pragma unroll
          for (int r2 = 0; r2 < 2; r2++) {
            union { float f; unsigned u; } e0, e1;
            e0.f = __builtin_amdgcn_exp2f(sacc[qt][kt][r2 * 2]     * SC);
            e1.f = __builtin_amdgcn_exp2f(sacc[qt][kt][r2 * 2 + 1] * SC);
            unsigned pk = __builtin_amdgcn_perm(e1.u + 0x8000u, e0.u + 0x8000u, 0x07060302u);
            int row = qt * 16 + quad * 4 + r2 * 2;
            myp[row * 40 + kt * 16 + l16]       = (unsigned short)pk;
            myp[(row + 1) * 40 + kt * 16 + l16] = (unsigned short)(pk >> 16);
          }
      bf16x8 pa0 = *(const bf16x8*)&myp[l16 * 40 + quad * 8];
      bf16x8 pa1 = *(const bf16x8*)&myp[(16 + l16) * 40 + quad * 8];
      lsum[0] = __builtin_amdgcn_mfma_f32_16x16x32_bf16(pa0, ones, lsum[0], 0, 0, 0);
      lsum[1] = __builtin_amdgcn_mfma_f32_16x16x32_bf16(pa1, ones, lsum[1], 0, 0, 0);
#pragma unroll
      for (int dt = 0; dt < 4; dt++) {
        bf16x8 vf = *(const bf16x8*)&lV[(dt * 16 + l16) * 64 + (((kc * 4 + quad) ^ fsw) * 8)];
        oacc[0][dt] = __builtin_amdgcn_mfma_f32_16x16x32_bf16(pa0, vf, oacc[0][dt], 0, 0, 0);
        oacc[1][dt] = __builtin_amdgcn_mfma_f32_16x16x32_bf16(pa1, vf, oacc[1][dt], 0, 0, 0);
      }
    }
    __syncthreads();
  }

  unsigned short* Od = Oa + (size_t)o * NTOK * 1024 + bh_off;
#pragma unroll
  for (int qt = 0; qt < 2; qt++)
#pragma unroll
    for (int dt = 0; dt < 4; dt++)
#pragma unroll
      for (int r = 0; r < 4; r++) {
        float val = oacc[qt][dt][r] / lsum[qt][r];
        Od[(size_t)(q0 + qt * 16 + quad * 4 + r) * 1024 + dt * 16 + l16] = f2bf(val);
      }
}

// ---------------- output GEMM: d_out[tok][s][:] = Oa[s] @ Wo + bo (fp32) ----------------
__global__ __launch_bounds__(256, 2) void gemm_out(
    const unsigned short* __restrict__ Oattn, const unsigned short* __restrict__ WtO,
    float* __restrict__ out, const float* __restrict__ bo)
{
  __shared__ alignas(16) unsigned short lA[128 * 32];
  __shared__ alignas(16) unsigned short lB[128 * 32];
  int s = blockIdx.z;
  f32x4 acc[4][4];
#pragma unroll
  for (int i = 0; i < 4; i++)
#pragma unroll
    for (int j = 0; j < 4; j++) acc[i][j] = (f32x4){0.f, 0.f, 0.f, 0.f};
  gemm128_core(Oattn + (size_t)s * NTOK * 1024, WtO, lA, lB, acc);

  int tid = threadIdx.x, wave = tid >> 6, lane = tid & 63, quad = lane >> 4, l16 = lane & 15;
  int m0 = blockIdx.x * 128 + (wave >> 1) * 64;
  int n0 = blockIdx.y * 128 + (wave & 1) * 64;
#pragma unroll
  for (int mi = 0; mi < 4; mi++)
#pragma unroll
    for (int ni = 0; ni < 4; ni++) {
      int col = n0 + ni * 16 + l16;
      float bcol = bo[col];
#pragma unroll
      for (int r = 0; r < 4; r++) {
        int row = m0 + mi * 16 + quad * 4 + r;
        out[(size_t)row * 3072 + s * 1024 + col] = acc[mi][ni][r] + bcol;
      }
    }
}

extern "C" void kernel_launch(void* const* d_in, const int* in_sizes, int n_in,
                              void* d_out, int out_size, void* d_ws, size_t ws_size,
                              hipStream_t stream) {
  (void)in_sizes; (void)n_in; (void)out_size; (void)ws_size;
  const float* x  = (const float*)d_in[0];
  const float* Wq = (const float*)d_in[1];
  const float* bq = (const float*)d_in[2];
  const float* Wk = (const float*)d_in[3];
  const float* bk = (const float*)d_in[4];
  const float* Wv = (const float*)d_in[5];
  const float* bv = (const float*)d_in[6];
  const float* Wo = (const float*)d_in[7];
  const float* bo = (const float*)d_in[8];
  float* out = (float*)d_out;

  char* ws = (char*)d_ws;
  // layout (bytes): Xbf 48MB (aliased by Vt after proj) | Wt 8MB | P 144MB | Oa 48MB
  unsigned short* Xbf = (unsigned short*)(ws + 0);
  unsigned short* Vt  = (unsigned short*)(ws + 0);          // alias: Xbf dead after gemm_proj
  unsigned short* Wt  = (unsigned short*)(ws + 50331648);
  unsigned short* P   = (unsigned short*)(ws + 58720256);
  unsigned short* Oa  = (unsigned short*)(ws + 209715200);

  convert_x<<<24576, 256, 0, stream>>>(x, Xbf);
  dim3 tb(32, 8), tg(32, 32);
  transpose_w<<<tg, tb, 0, stream>>>(Wq, Wt + 0 * 1048576);
  transpose_w<<<tg, tb, 0, stream>>>(Wk, Wt + 1 * 1048576);
  transpose_w<<<tg, tb, 0, stream>>>(Wv, Wt + 2 * 1048576);
  transpose_w<<<tg, tb, 0, stream>>>(Wo, Wt + 3 * 1048576);

  gemm_proj<<<dim3(64, 8, 9), 256, 0, stream>>>(Xbf, Wt, P, bq, bk, bv);
  transpose_v<<<dim3(16, 1, 384), dim3(64, 8), 0, stream>>>(P, Vt);
  attn<<<dim3(128, 8, 3), 256, 0, stream>>>(P, Vt, Oa);
  gemm_out<<<dim3(64, 8, 3), 256, 0, stream>>>(Oa, Wt + 3 * 1048576, out, bo);
}